// Round 9
// baseline (235.061 us; speedup 1.0000x reference)
//
#include <hip/hip_runtime.h>
#include <math.h>

#define B_ 4
#define T_ 1024
#define D_ 1024
#define H_ 16
#define DH_ 64
#define NCAT 2112   // 1024 (Q) + 1024 (K) + 64 (V)

typedef unsigned short u16;
typedef unsigned int u32;
typedef __attribute__((ext_vector_type(8))) short bf16x8;
typedef __attribute__((ext_vector_type(4))) float f32x4;

__device__ __forceinline__ u16 bf16rne(float f) {
  u32 u = __float_as_uint(f);
  u32 r = (u + 0x7fffu + ((u >> 16) & 1u)) >> 16;
  return (u16)r;
}
__device__ __forceinline__ float bf16tof(u16 h) {
  return __uint_as_float((u32)h << 16);
}

// async global->LDS, 16B per lane; LDS dest = wave-uniform base + lane*16
__device__ __forceinline__ void gload_lds16(const u16* g, u16* l) {
  __builtin_amdgcn_global_load_lds(
      (const __attribute__((address_space(1))) unsigned int*)g,
      (__attribute__((address_space(3))) unsigned int*)l, 16, 0, 0);
}

// ---------------------------------------------------------------------------
// wprep: all weight transposes + split-converts + bias concat in ONE launch.
// ---------------------------------------------------------------------------
__global__ __launch_bounds__(256) void wprep(
    const float* __restrict__ Wq, const float* __restrict__ Wk,
    const float* __restrict__ Wv, const float* __restrict__ Wo,
    const float* __restrict__ bq, const float* __restrict__ bk,
    const float* __restrict__ bv,
    u16* __restrict__ WcThi, u16* __restrict__ WcTlo,
    u16* __restrict__ WoThi, u16* __restrict__ WoTlo,
    float* __restrict__ bcat) {
  const int blk = blockIdx.x;
  if (blk == 784) {
    for (int i = threadIdx.x; i < NCAT; i += 256)
      bcat[i] = (i < 1024) ? bq[i] : ((i < 2048) ? bk[i - 1024] : bv[i - 2048]);
    return;
  }
  const float* W;
  u16 *Thi, *Tlo;
  int roff, Nw, bx, by;
  if (blk < 256)      { W = Wq; Thi = WcThi; Tlo = WcTlo; roff = 0;    Nw = 1024; bx = blk & 15;        by = blk >> 4; }
  else if (blk < 512) { W = Wk; Thi = WcThi; Tlo = WcTlo; roff = 1024; Nw = 1024; bx = (blk - 256) & 15; by = (blk - 256) >> 4; }
  else if (blk < 768) { W = Wo; Thi = WoThi; Tlo = WoTlo; roff = 0;    Nw = 1024; bx = (blk - 512) & 15; by = (blk - 512) >> 4; }
  else                { W = Wv; Thi = WcThi; Tlo = WcTlo; roff = 2048; Nw = 64;   bx = 0;               by = blk - 768; }

  __shared__ float Ws[64][65];
  const int t = threadIdx.x;
  const int n0 = bx * 64, k0 = by * 64;
#pragma unroll
  for (int rr = 0; rr < 4; rr++) {
    int r = rr * 16 + (t >> 4);
    int c = (t & 15) * 4;
    float4 v = *(const float4*)&W[(size_t)(k0 + r) * Nw + n0 + c];
    Ws[r][c] = v.x; Ws[r][c + 1] = v.y; Ws[r][c + 2] = v.z; Ws[r][c + 3] = v.w;
  }
  __syncthreads();
  const int n = t >> 2, kc = t & 3;
  u32 uh[8], ul[8];
#pragma unroll
  for (int j2 = 0; j2 < 8; j2++) {
    u16 hh[2], ll[2];
#pragma unroll
    for (int e = 0; e < 2; e++) {
      float v = Ws[kc * 16 + j2 * 2 + e][n];
      u16 h = bf16rne(v);
      hh[e] = h;
      ll[e] = bf16rne(v - bf16tof(h));
    }
    uh[j2] = (u32)hh[0] | ((u32)hh[1] << 16);
    ul[j2] = (u32)ll[0] | ((u32)ll[1] << 16);
  }
  size_t base = (size_t)(roff + n0 + n) * 1024 + k0 + kc * 16;
  *(uint4*)&Thi[base]     = make_uint4(uh[0], uh[1], uh[2], uh[3]);
  *(uint4*)&Thi[base + 8] = make_uint4(uh[4], uh[5], uh[6], uh[7]);
  *(uint4*)&Tlo[base]     = make_uint4(ul[0], ul[1], ul[2], ul[3]);
  *(uint4*)&Tlo[base + 8] = make_uint4(ul[4], ul[5], ul[6], ul[7]);
}

// ---------------------------------------------------------------------------
// Row-major split-convert: in fp32 [4096*1024] -> hi/lo bf16, same layout.
// ---------------------------------------------------------------------------
__global__ __launch_bounds__(256) void rowconv(
    const float* __restrict__ in, u16* __restrict__ hi, u16* __restrict__ lo) {
  size_t i = ((size_t)blockIdx.x * 256 + threadIdx.x) * 8;
  float4 v0 = *(const float4*)&in[i];
  float4 v1 = *(const float4*)&in[i + 4];
  float vv[8] = {v0.x, v0.y, v0.z, v0.w, v1.x, v1.y, v1.z, v1.w};
  u32 uh[4], ul[4];
#pragma unroll
  for (int j = 0; j < 4; j++) {
    u16 h0 = bf16rne(vv[2 * j]);
    u16 h1 = bf16rne(vv[2 * j + 1]);
    u16 l0 = bf16rne(vv[2 * j] - bf16tof(h0));
    u16 l1 = bf16rne(vv[2 * j + 1] - bf16tof(h1));
    uh[j] = (u32)h0 | ((u32)h1 << 16);
    ul[j] = (u32)l0 | ((u32)l1 << 16);
  }
  *(uint4*)&hi[i] = make_uint4(uh[0], uh[1], uh[2], uh[3]);
  *(uint4*)&lo[i] = make_uint4(ul[0], ul[1], ul[2], ul[3]);
}

// ---------------------------------------------------------------------------
// Split-bf16 MFMA GEMM, m97-style staging (global_load_lds 16B, linear LDS),
// TM x 128 tile, BK=32, 4 waves (2x2). MFMA operands SWAPPED: mfma(B,A)
// gives D[n][m] -> thread holds 4 consecutive n at fixed m -> vector stores.
// QKV=true: panels y<8 3-pass -> Qhi/Qlo; y>=8 2-pass -> Khi / Vt.
// QKV=false: 3-pass, fp32 C + bias, float4 stores (Wo projection).
// ---------------------------------------------------------------------------
template <int TM, bool QKV>
__global__ __launch_bounds__(256) void mfma_gemm(
    const u16* __restrict__ Ahi, const u16* __restrict__ Alo,
    const u16* __restrict__ Bhi, const u16* __restrict__ Blo,
    const float* __restrict__ bias, float* __restrict__ C,
    int Nvalid, int Kd, int ldc,
    u16* __restrict__ Qhi, u16* __restrict__ Qlo,
    u16* __restrict__ Khi, u16* __restrict__ Vt) {
  constexpr int MF = TM / 32;   // M-fragments per wave
  constexpr int AC = TM / 64;   // A 1KB-chunks per wave per array
  __shared__ u16 Ah[TM][32];
  __shared__ u16 Al[TM][32];
  __shared__ u16 Bh[128][32];
  __shared__ u16 Bl[128][32];
  const int tid = threadIdx.x;
  const int lane = tid & 63, wid = tid >> 6;
  const int wr = wid >> 1, wc = wid & 1;
  const int m0 = blockIdx.x * TM, n0 = blockIdx.y * 128;
  const bool full3 = !QKV || (blockIdx.y < 8);
  f32x4 acc[MF][4];
#pragma unroll
  for (int i = 0; i < MF; i++)
#pragma unroll
    for (int j = 0; j < 4; j++) {
      acc[i][j][0] = 0.f; acc[i][j][1] = 0.f;
      acc[i][j][2] = 0.f; acc[i][j][3] = 0.f;
    }
  const int fo = 8 * (lane >> 4);
  const int fr = lane & 15;
  const int srow = lane >> 2;        // row within a 16-row chunk
  const int scol = (lane & 3) * 8;   // u16 col within BK=32

#pragma unroll 1
  for (int k0 = 0; k0 < Kd; k0 += 32) {
#pragma unroll
    for (int c = 0; c < AC; c++) {
      int chunk = wid * AC + c;
      size_t ga = (size_t)(m0 + chunk * 16 + srow) * Kd + k0 + scol;
      gload_lds16(&Ahi[ga], ((u16*)Ah) + chunk * 512);
      if (full3) gload_lds16(&Alo[ga], ((u16*)Al) + chunk * 512);
    }
#pragma unroll
    for (int c = 0; c < 2; c++) {
      int chunk = wid * 2 + c;
      int grow = n0 + chunk * 16 + srow;
      if (grow >= Nvalid) grow = Nvalid - 1;  // clamp; epilogue masks
      size_t gb = (size_t)grow * Kd + k0 + scol;
      gload_lds16(&Bhi[gb], ((u16*)Bh) + chunk * 512);
      gload_lds16(&Blo[gb], ((u16*)Bl) + chunk * 512);
    }
    __syncthreads();
    bf16x8 bhf[4], blf[4];
#pragma unroll
    for (int nf = 0; nf < 4; nf++) {
      int r = wc * 64 + nf * 16 + fr;
      bhf[nf] = *(bf16x8*)&Bh[r][fo];
      blf[nf] = *(bf16x8*)&Bl[r][fo];
    }
#pragma unroll
    for (int mf = 0; mf < MF; mf++) {
      int r = wr * (TM / 2) + mf * 16 + fr;
      bf16x8 ahf = *(bf16x8*)&Ah[r][fo];
#pragma unroll
      for (int nf = 0; nf < 4; nf++) {
        acc[mf][nf] = __builtin_amdgcn_mfma_f32_16x16x32_bf16(bhf[nf], ahf, acc[mf][nf], 0, 0, 0);
        acc[mf][nf] = __builtin_amdgcn_mfma_f32_16x16x32_bf16(blf[nf], ahf, acc[mf][nf], 0, 0, 0);
      }
      if (full3) {
        bf16x8 alf = *(bf16x8*)&Al[r][fo];
#pragma unroll
        for (int nf = 0; nf < 4; nf++)
          acc[mf][nf] = __builtin_amdgcn_mfma_f32_16x16x32_bf16(bhf[nf], alf, acc[mf][nf], 0, 0, 0);
      }
    }
    __syncthreads();
  }
  // D transposed: row(4*rq+r) = n within nf-tile, col(fr) = m within mf-tile
  const int rq = lane >> 4;
#pragma unroll
  for (int mf = 0; mf < MF; mf++) {
    int m = m0 + wr * (TM / 2) + mf * 16 + fr;
#pragma unroll
    for (int nf = 0; nf < 4; nf++) {
      int nb = n0 + wc * 64 + nf * 16 + rq * 4;
      if (nb < Nvalid) {
        float4 b4 = *(const float4*)&bias[nb];
        float v0 = acc[mf][nf][0] + b4.x;
        float v1 = acc[mf][nf][1] + b4.y;
        float v2 = acc[mf][nf][2] + b4.z;
        float v3 = acc[mf][nf][3] + b4.w;
        if constexpr (QKV) {
          if (nb < 1024) {               // Q: split hi/lo, uint2-packed
            u16 h0 = bf16rne(v0), h1 = bf16rne(v1);
            u16 h2 = bf16rne(v2), h3 = bf16rne(v3);
            *(uint2*)&Qhi[(size_t)m * 1024 + nb] =
                make_uint2((u32)h0 | ((u32)h1 << 16), (u32)h2 | ((u32)h3 << 16));
            u16 l0 = bf16rne(v0 - bf16tof(h0)), l1 = bf16rne(v1 - bf16tof(h1));
            u16 l2 = bf16rne(v2 - bf16tof(h2)), l3 = bf16rne(v3 - bf16tof(h3));
            *(uint2*)&Qlo[(size_t)m * 1024 + nb] =
                make_uint2((u32)l0 | ((u32)l1 << 16), (u32)l2 | ((u32)l3 << 16));
          } else if (nb < 2048) {        // K: hi bf16, uint2-packed
            *(uint2*)&Khi[(size_t)m * 1024 + (nb - 1024)] =
                make_uint2((u32)bf16rne(v0) | ((u32)bf16rne(v1) << 16),
                           (u32)bf16rne(v2) | ((u32)bf16rne(v3) << 16));
          } else {                       // V: transposed; contiguous in m
            Vt[(size_t)(nb - 2048 + 0) * 4096 + m] = bf16rne(v0);
            Vt[(size_t)(nb - 2048 + 1) * 4096 + m] = bf16rne(v1);
            Vt[(size_t)(nb - 2048 + 2) * 4096 + m] = bf16rne(v2);
            Vt[(size_t)(nb - 2048 + 3) * 4096 + m] = bf16rne(v3);
          }
        } else {
          float4 o; o.x = v0; o.y = v1; o.z = v2; o.w = v3;
          *(float4*)&C[(size_t)m * ldc + nb] = o;
        }
      }
    }
  }
}

// ---------------------------------------------------------------------------
// MFMA flash attention. grid = B*H*(T/64) = 1024 blocks, 256 thr (4 waves).
// S via mfma(Kh, Qhi/Qlo): D[k][q], q = l15. PV SWAPPED: mfma(V, P) ->
// O[d][q=l15] -> rescale/li are lane-local, out stores uint2-packed.
// ---------------------------------------------------------------------------
__global__ __launch_bounds__(256) void attn_fused_mfma(
    const u16* __restrict__ Qhi, const u16* __restrict__ Qlo,
    const u16* __restrict__ Khi, const u16* __restrict__ Vt,
    float* __restrict__ mrow, float* __restrict__ linv,
    u16* __restrict__ ophi, u16* __restrict__ oplo) {
  __shared__ u16 Kh_s[64][72];
  __shared__ u16 Vt_s[64][72];
  __shared__ u16 P_s[4][16][72];
  const int bi = blockIdx.x;
  const int qt = bi & 15, h = (bi >> 4) & 15, b = bi >> 8;
  const int tid = threadIdx.x;
  const int lane = tid & 63, w = tid >> 6;
  const int l15 = lane & 15, g = lane >> 4;
  const int q0 = qt * 64 + w * 16;
  const float scale = 0.125f;
  bf16x8 qh[2], ql[2];
  {
    size_t qoff = (size_t)(b * T_ + q0 + l15) * 1024 + h * DH_;
    qh[0] = *(const bf16x8*)&Qhi[qoff + 8 * g];
    qh[1] = *(const bf16x8*)&Qhi[qoff + 32 + 8 * g];
    ql[0] = *(const bf16x8*)&Qlo[qoff + 8 * g];
    ql[1] = *(const bf16x8*)&Qlo[qoff + 32 + 8 * g];
  }
  float m_run = -1e30f, l_run = 0.f;
  f32x4 acc_o[4];
#pragma unroll
  for (int nf = 0; nf < 4; nf++) {
    acc_o[nf][0] = 0.f; acc_o[nf][1] = 0.f; acc_o[nf][2] = 0.f; acc_o[nf][3] = 0.f;
  }

#pragma unroll 1
  for (int kt = 0; kt < 16; kt++) {
    {
      int r = tid >> 2, cs = (tid & 3) * 16;
      size_t krow = (size_t)(b * T_ + kt * 64 + r) * 1024 + h * DH_ + cs;
      *(uint4*)&Kh_s[r][cs]     = *(const uint4*)&Khi[krow];
      *(uint4*)&Kh_s[r][cs + 8] = *(const uint4*)&Khi[krow + 8];
      size_t vrow = (size_t)r * 4096 + b * T_ + kt * 64 + cs;
      *(uint4*)&Vt_s[r][cs]     = *(const uint4*)&Vt[vrow];
      *(uint4*)&Vt_s[r][cs + 8] = *(const uint4*)&Vt[vrow + 8];
    }
    __syncthreads();
    f32x4 accs[4];
#pragma unroll
    for (int mf = 0; mf < 4; mf++) {
      accs[mf][0] = 0.f; accs[mf][1] = 0.f; accs[mf][2] = 0.f; accs[mf][3] = 0.f;
    }
#pragma unroll
    for (int mf = 0; mf < 4; mf++) {
#pragma unroll
      for (int ks = 0; ks < 2; ks++) {
        bf16x8 kh = *(bf16x8*)&Kh_s[mf * 16 + l15][ks * 32 + 8 * g];
        accs[mf] = __builtin_amdgcn_mfma_f32_16x16x32_bf16(kh, qh[ks], accs[mf], 0, 0, 0);
        accs[mf] = __builtin_amdgcn_mfma_f32_16x16x32_bf16(kh, ql[ks], accs[mf], 0, 0, 0);
      }
    }
    float tm = -1e30f;
#pragma unroll
    for (int mf = 0; mf < 4; mf++)
#pragma unroll
      for (int r = 0; r < 4; r++) {
        accs[mf][r] *= scale;
        tm = fmaxf(tm, accs[mf][r]);
      }
    tm = fmaxf(tm, __shfl_xor(tm, 16));
    tm = fmaxf(tm, __shfl_xor(tm, 32));
    float m_new = fmaxf(m_run, tm);
    float crs = __expf(m_run - m_new);
    float ts = 0.f;
#pragma unroll
    for (int mf = 0; mf < 4; mf++) {
      float p0 = __expf(accs[mf][0] - m_new);
      float p1 = __expf(accs[mf][1] - m_new);
      float p2 = __expf(accs[mf][2] - m_new);
      float p3 = __expf(accs[mf][3] - m_new);
      ts += (p0 + p1) + (p2 + p3);
      u32 w0 = (u32)bf16rne(p0) | ((u32)bf16rne(p1) << 16);
      u32 w1 = (u32)bf16rne(p2) | ((u32)bf16rne(p3) << 16);
      *(uint2*)&P_s[w][l15][16 * mf + 4 * g] = make_uint2(w0, w1);
    }
    ts += __shfl_xor(ts, 16);
    ts += __shfl_xor(ts, 32);
    l_run = l_run * crs + ts;
    m_run = m_new;
    __syncthreads();
    // PV (swapped): O[d][q=l15]; rescale by lane-local crs
#pragma unroll
    for (int nf = 0; nf < 4; nf++)
#pragma unroll
      for (int r = 0; r < 4; r++) acc_o[nf][r] *= crs;
    bf16x8 pa[2];
    pa[0] = *(bf16x8*)&P_s[w][l15][8 * g];
    pa[1] = *(bf16x8*)&P_s[w][l15][32 + 8 * g];
#pragma unroll
    for (int nf = 0; nf < 4; nf++) {
#pragma unroll
      for (int ks = 0; ks < 2; ks++) {
        bf16x8 vb = *(bf16x8*)&Vt_s[nf * 16 + l15][ks * 32 + 8 * g];
        acc_o[nf] = __builtin_amdgcn_mfma_f32_16x16x32_bf16(vb, pa[ks], acc_o[nf], 0, 0, 0);
      }
    }
    __syncthreads();
  }
  float li = 1.0f / l_run;
  if (g == 0) {
    int idx = (b * H_ + h) * T_ + q0 + l15;
    mrow[idx] = m_run;
    linv[idx] = li;
  }
  // out: d = nf*16 + 4g + r (4 consecutive), q = l15 -> uint2-packed stores
  size_t obase = (size_t)(b * T_ + q0 + l15) * D_ + h * DH_;
#pragma unroll
  for (int nf = 0; nf < 4; nf++) {
    float v0 = acc_o[nf][0] * li, v1 = acc_o[nf][1] * li;
    float v2 = acc_o[nf][2] * li, v3 = acc_o[nf][3] * li;
    u16 h0 = bf16rne(v0), h1 = bf16rne(v1);
    u16 h2 = bf16rne(v2), h3 = bf16rne(v3);
    *(uint2*)&ophi[obase + nf * 16 + 4 * g] =
        make_uint2((u32)h0 | ((u32)h1 << 16), (u32)h2 | ((u32)h3 << 16));
    u16 l0 = bf16rne(v0 - bf16tof(h0)), l1 = bf16rne(v1 - bf16tof(h1));
    u16 l2 = bf16rne(v2 - bf16tof(h2)), l3 = bf16rne(v3 - bf16tof(h3));
    *(uint2*)&oplo[obase + nf * 16 + 4 * g] =
        make_uint2((u32)l0 | ((u32)l1 << 16), (u32)l2 | ((u32)l3 << 16));
  }
}

// ---------------------------------------------------------------------------
// MFMA attn_mean. grid = B*(T/64)*(T/64) = 1024 blocks. 1-pass S (Qhi only).
// ---------------------------------------------------------------------------
__global__ __launch_bounds__(256) void attn_mean_mfma(
    const u16* __restrict__ Qhi, const u16* __restrict__ Khi,
    const float* __restrict__ mrow, const float* __restrict__ linv,
    float* __restrict__ am_out) {
  __shared__ u16 Kh_s[64][72];
  const int bi = blockIdx.x;
  const int kc = bi & 15, qt = (bi >> 4) & 15, b = bi >> 8;
  const int tid = threadIdx.x;
  const int lane = tid & 63, w = tid >> 6;
  const int l15 = lane & 15, g = lane >> 4;
  const int q0 = qt * 64 + w * 16, k0 = kc * 64;
  const float scale = 0.125f;
  float am[4][4] = {};
#pragma unroll 1
  for (int h = 0; h < H_; h++) {
    {
      int r = tid >> 2, cs = (tid & 3) * 16;
      size_t krow = (size_t)(b * T_ + k0 + r) * 1024 + h * DH_ + cs;
      *(uint4*)&Kh_s[r][cs]     = *(const uint4*)&Khi[krow];
      *(uint4*)&Kh_s[r][cs + 8] = *(const uint4*)&Khi[krow + 8];
    }
    __syncthreads();
    bf16x8 qh[2];
    {
      size_t qoff = (size_t)(b * T_ + q0 + l15) * 1024 + h * DH_;
      qh[0] = *(const bf16x8*)&Qhi[qoff + 8 * g];
      qh[1] = *(const bf16x8*)&Qhi[qoff + 32 + 8 * g];
    }
    f32x4 accs[4];
#pragma unroll
    for (int mf = 0; mf < 4; mf++) {
      accs[mf][0] = 0.f; accs[mf][1] = 0.f; accs[mf][2] = 0.f; accs[mf][3] = 0.f;
    }
#pragma unroll
    for (int mf = 0; mf < 4; mf++) {
#pragma unroll
      for (int ks = 0; ks < 2; ks++) {
        bf16x8 kh = *(bf16x8*)&Kh_s[mf * 16 + l15][ks * 32 + 8 * g];
        accs[mf] = __builtin_amdgcn_mfma_f32_16x16x32_bf16(kh, qh[ks], accs[mf], 0, 0, 0);
      }
    }
    const float mq = mrow[(b * H_ + h) * T_ + q0 + l15];
    const float li = linv[(b * H_ + h) * T_ + q0 + l15];
#pragma unroll
    for (int mf = 0; mf < 4; mf++)
#pragma unroll
      for (int r = 0; r < 4; r++)
        am[mf][r] += __expf(accs[mf][r] * scale - mq) * li;
    __syncthreads();
  }
  const float inv16 = 1.0f / 16.0f;
#pragma unroll
  for (int mf = 0; mf < 4; mf++) {
    float4 o;
    o.x = am[mf][0] * inv16; o.y = am[mf][1] * inv16;
    o.z = am[mf][2] * inv16; o.w = am[mf][3] * inv16;
    *(float4*)&am_out[(size_t)(b * T_ + q0 + l15) * T_ + k0 + 16 * mf + 4 * g] = o;
  }
}

// ---------------------------------------------------------------------------
extern "C" void kernel_launch(void* const* d_in, const int* in_sizes, int n_in,
                              void* d_out, int out_size, void* d_ws, size_t ws_size,
                              hipStream_t stream) {
  const float* x  = (const float*)d_in[0];
  const float* Wq = (const float*)d_in[1];
  const float* bq = (const float*)d_in[2];
  const float* Wk = (const float*)d_in[3];
  const float* bk = (const float*)d_in[4];
  const float* Wv = (const float*)d_in[5];
  const float* bv = (const float*)d_in[6];
  const float* Wo = (const float*)d_in[7];
  const float* bo = (const float*)d_in[8];

  float* out = (float*)d_out;                      // [B,T,D]
  float* am  = out + (size_t)B_ * T_ * D_;         // [B,T,T]

  char* w = (char*)d_ws;
  u16* Qhi   = (u16*)w; w += (size_t)4096 * 1024 * 2;
  u16* Qlo   = (u16*)w; w += (size_t)4096 * 1024 * 2;
  u16* Khi   = (u16*)w; w += (size_t)4096 * 1024 * 2;
  u16* Vt    = (u16*)w; w += (size_t)64 * 4096 * 2;
  u16* xhi   = (u16*)w; w += (size_t)4096 * 1024 * 2;  // x-split, then out_pre hi
  u16* xlo   = (u16*)w; w += (size_t)4096 * 1024 * 2;  // x-split, then out_pre lo
  u16* WcThi = (u16*)w; w += (size_t)NCAT * 1024 * 2;
  u16* WcTlo = (u16*)w; w += (size_t)NCAT * 1024 * 2;
  u16* WoThi = (u16*)w; w += (size_t)1024 * 1024 * 2;
  u16* WoTlo = (u16*)w; w += (size_t)1024 * 1024 * 2;
  float* mrow  = (float*)w; w += (size_t)B_ * H_ * T_ * 4;
  float* linvp = (float*)w; w += (size_t)B_ * H_ * T_ * 4;
  float* bcat  = (float*)w; w += (size_t)NCAT * 4;

  wprep<<<785, 256, 0, stream>>>(Wq, Wk, Wv, Wo, bq, bk, bv,
                                 WcThi, WcTlo, WoThi, WoTlo, bcat);
  rowconv<<<2048, 256, 0, stream>>>(x, xhi, xlo);

  // QKV GEMM -> Qhi/Qlo (split), Khi (bf16), Vt (bf16 transposed)
  mfma_gemm<128, true><<<dim3(32, 17), 256, 0, stream>>>(
      xhi, xlo, WcThi, WcTlo, bcat, nullptr, NCAT, 1024, 0,
      Qhi, Qlo, Khi, Vt);

  attn_fused_mfma<<<1024, 256, 0, stream>>>(Qhi, Qlo, Khi, Vt,
                                            mrow, linvp, xhi, xlo);
  attn_mean_mfma<<<1024, 256, 0, stream>>>(Qhi, Khi, mrow, linvp, am);

  mfma_gemm<64, false><<<dim3(64, 8), 256, 0, stream>>>(
      xhi, xlo, WoThi, WoTlo, bo, out, 1024, 1024, 1024,
      nullptr, nullptr, nullptr, nullptr);
}

// Round 10
// 174.333 us; speedup vs baseline: 1.3483x; 1.3483x over previous
//
#include <hip/hip_runtime.h>
#include <math.h>

#define B_ 4
#define T_ 1024
#define D_ 1024
#define H_ 16
#define DH_ 64
#define NCAT 2112   // 1024 (Q) + 1024 (K) + 64 (V)

typedef unsigned short u16;
typedef unsigned int u32;
typedef __attribute__((ext_vector_type(8))) short bf16x8;
typedef __attribute__((ext_vector_type(4))) float f32x4;

__device__ __forceinline__ u16 bf16rne(float f) {
  u32 u = __float_as_uint(f);
  u32 r = (u + 0x7fffu + ((u >> 16) & 1u)) >> 16;
  return (u16)r;
}
__device__ __forceinline__ float bf16tof(u16 h) {
  return __uint_as_float((u32)h << 16);
}

// async global->LDS, 16B per lane; LDS dest = wave-uniform base + lane*16
__device__ __forceinline__ void gload_lds16(const u16* g, u16* l) {
  __builtin_amdgcn_global_load_lds(
      (const __attribute__((address_space(1))) unsigned int*)g,
      (__attribute__((address_space(3))) unsigned int*)l, 16, 0, 0);
}

// ---------------------------------------------------------------------------
// wprep: weight transposes + split-converts + bias concat in ONE launch.
// Wq/Wk/Wv -> WcT hi+lo (2-pass QKV GEMM needs W split). Wo -> hi only
// (1-pass Wo GEMM). Block 784: bias concat.
// ---------------------------------------------------------------------------
__global__ __launch_bounds__(256) void wprep(
    const float* __restrict__ Wq, const float* __restrict__ Wk,
    const float* __restrict__ Wv, const float* __restrict__ Wo,
    const float* __restrict__ bq, const float* __restrict__ bk,
    const float* __restrict__ bv,
    u16* __restrict__ WcThi, u16* __restrict__ WcTlo,
    u16* __restrict__ WoThi, float* __restrict__ bcat) {
  const int blk = blockIdx.x;
  if (blk == 784) {
    for (int i = threadIdx.x; i < NCAT; i += 256)
      bcat[i] = (i < 1024) ? bq[i] : ((i < 2048) ? bk[i - 1024] : bv[i - 2048]);
    return;
  }
  const float* W;
  u16 *Thi, *Tlo;
  int roff, Nw, bx, by;
  if (blk < 256)      { W = Wq; Thi = WcThi; Tlo = WcTlo; roff = 0;    Nw = 1024; bx = blk & 15;        by = blk >> 4; }
  else if (blk < 512) { W = Wk; Thi = WcThi; Tlo = WcTlo; roff = 1024; Nw = 1024; bx = (blk - 256) & 15; by = (blk - 256) >> 4; }
  else if (blk < 768) { W = Wo; Thi = WoThi; Tlo = nullptr; roff = 0;  Nw = 1024; bx = (blk - 512) & 15; by = (blk - 512) >> 4; }
  else                { W = Wv; Thi = WcThi; Tlo = WcTlo; roff = 2048; Nw = 64;   bx = 0;               by = blk - 768; }

  __shared__ float Ws[64][65];
  const int t = threadIdx.x;
  const int n0 = bx * 64, k0 = by * 64;
#pragma unroll
  for (int rr = 0; rr < 4; rr++) {
    int r = rr * 16 + (t >> 4);
    int c = (t & 15) * 4;
    float4 v = *(const float4*)&W[(size_t)(k0 + r) * Nw + n0 + c];
    Ws[r][c] = v.x; Ws[r][c + 1] = v.y; Ws[r][c + 2] = v.z; Ws[r][c + 3] = v.w;
  }
  __syncthreads();
  const int n = t >> 2, kc = t & 3;
  u32 uh[8], ul[8];
#pragma unroll
  for (int j2 = 0; j2 < 8; j2++) {
    u16 hh[2], ll[2];
#pragma unroll
    for (int e = 0; e < 2; e++) {
      float v = Ws[kc * 16 + j2 * 2 + e][n];
      u16 h = bf16rne(v);
      hh[e] = h;
      ll[e] = bf16rne(v - bf16tof(h));
    }
    uh[j2] = (u32)hh[0] | ((u32)hh[1] << 16);
    ul[j2] = (u32)ll[0] | ((u32)ll[1] << 16);
  }
  size_t base = (size_t)(roff + n0 + n) * 1024 + k0 + kc * 16;
  *(uint4*)&Thi[base]     = make_uint4(uh[0], uh[1], uh[2], uh[3]);
  *(uint4*)&Thi[base + 8] = make_uint4(uh[4], uh[5], uh[6], uh[7]);
  if (Tlo != nullptr) {
    *(uint4*)&Tlo[base]     = make_uint4(ul[0], ul[1], ul[2], ul[3]);
    *(uint4*)&Tlo[base + 8] = make_uint4(ul[4], ul[5], ul[6], ul[7]);
  }
}

// ---------------------------------------------------------------------------
// Row-major bf16 round: in fp32 [4096*1024] -> hi bf16, same layout.
// ---------------------------------------------------------------------------
__global__ __launch_bounds__(256) void rowconv(
    const float* __restrict__ in, u16* __restrict__ hi) {
  size_t i = ((size_t)blockIdx.x * 256 + threadIdx.x) * 8;
  float4 v0 = *(const float4*)&in[i];
  float4 v1 = *(const float4*)&in[i + 4];
  float vv[8] = {v0.x, v0.y, v0.z, v0.w, v1.x, v1.y, v1.z, v1.w};
  u32 uh[4];
#pragma unroll
  for (int j = 0; j < 4; j++) {
    uh[j] = (u32)bf16rne(vv[2 * j]) | ((u32)bf16rne(vv[2 * j + 1]) << 16);
  }
  *(uint4*)&hi[i] = make_uint4(uh[0], uh[1], uh[2], uh[3]);
}

// ---------------------------------------------------------------------------
// bf16 MFMA GEMM, m97-style staging (global_load_lds 16B, linear LDS),
// TM x 128 tile, BK=32, 4 waves (2x2). MFMA operands SWAPPED: mfma(B,A)
// gives D[n][m] -> thread holds 4 consecutive n at fixed m -> vector stores.
// QKV=true: 2-pass (Ah@Bh + Ah@Bl, W split) -> Qhi/Qlo | Khi | Vt.
// QKV=false: 1-pass (Ah@Bh) -> fp32 C + bias (Wo projection).
// ---------------------------------------------------------------------------
template <int TM, bool QKV>
__global__ __launch_bounds__(256) void mfma_gemm(
    const u16* __restrict__ Ahi, const u16* __restrict__ Bhi,
    const u16* __restrict__ Blo, const float* __restrict__ bias,
    float* __restrict__ C, int Nvalid, int Kd, int ldc,
    u16* __restrict__ Qhi, u16* __restrict__ Qlo,
    u16* __restrict__ Khi, u16* __restrict__ Vt) {
  constexpr int MF = TM / 32;   // M-fragments per wave
  constexpr int AC = TM / 64;   // A 1KB-chunks per wave
  __shared__ u16 Ah[TM][32];
  __shared__ u16 Bh[128][32];
  __shared__ u16 Bl[QKV ? 128 : 1][32];
  const int tid = threadIdx.x;
  const int lane = tid & 63, wid = tid >> 6;
  const int wr = wid >> 1, wc = wid & 1;
  const int m0 = blockIdx.x * TM, n0 = blockIdx.y * 128;
  f32x4 acc[MF][4];
#pragma unroll
  for (int i = 0; i < MF; i++)
#pragma unroll
    for (int j = 0; j < 4; j++) {
      acc[i][j][0] = 0.f; acc[i][j][1] = 0.f;
      acc[i][j][2] = 0.f; acc[i][j][3] = 0.f;
    }
  const int fo = 8 * (lane >> 4);
  const int fr = lane & 15;
  const int srow = lane >> 2;        // row within a 16-row chunk
  const int scol = (lane & 3) * 8;   // u16 col within BK=32

#pragma unroll 1
  for (int k0 = 0; k0 < Kd; k0 += 32) {
#pragma unroll
    for (int c = 0; c < AC; c++) {
      int chunk = wid * AC + c;
      size_t ga = (size_t)(m0 + chunk * 16 + srow) * Kd + k0 + scol;
      gload_lds16(&Ahi[ga], ((u16*)Ah) + chunk * 512);
    }
#pragma unroll
    for (int c = 0; c < 2; c++) {
      int chunk = wid * 2 + c;
      int grow = n0 + chunk * 16 + srow;
      if (grow >= Nvalid) grow = Nvalid - 1;  // clamp; epilogue masks
      size_t gb = (size_t)grow * Kd + k0 + scol;
      gload_lds16(&Bhi[gb], ((u16*)Bh) + chunk * 512);
      if constexpr (QKV) gload_lds16(&Blo[gb], ((u16*)Bl) + chunk * 512);
    }
    __syncthreads();
    bf16x8 bhf[4], blf[4];
#pragma unroll
    for (int nf = 0; nf < 4; nf++) {
      int r = wc * 64 + nf * 16 + fr;
      bhf[nf] = *(bf16x8*)&Bh[r][fo];
      if constexpr (QKV) blf[nf] = *(bf16x8*)&Bl[r][fo];
    }
#pragma unroll
    for (int mf = 0; mf < MF; mf++) {
      int r = wr * (TM / 2) + mf * 16 + fr;
      bf16x8 ahf = *(bf16x8*)&Ah[r][fo];
#pragma unroll
      for (int nf = 0; nf < 4; nf++) {
        acc[mf][nf] = __builtin_amdgcn_mfma_f32_16x16x32_bf16(bhf[nf], ahf, acc[mf][nf], 0, 0, 0);
        if constexpr (QKV)
          acc[mf][nf] = __builtin_amdgcn_mfma_f32_16x16x32_bf16(blf[nf], ahf, acc[mf][nf], 0, 0, 0);
      }
    }
    __syncthreads();
  }
  // D transposed: row(4*rq+r) = n within nf-tile, col(fr) = m within mf-tile
  const int rq = lane >> 4;
#pragma unroll
  for (int mf = 0; mf < MF; mf++) {
    int m = m0 + wr * (TM / 2) + mf * 16 + fr;
#pragma unroll
    for (int nf = 0; nf < 4; nf++) {
      int nb = n0 + wc * 64 + nf * 16 + rq * 4;
      if (nb < Nvalid) {
        float4 b4 = *(const float4*)&bias[nb];
        float v0 = acc[mf][nf][0] + b4.x;
        float v1 = acc[mf][nf][1] + b4.y;
        float v2 = acc[mf][nf][2] + b4.z;
        float v3 = acc[mf][nf][3] + b4.w;
        if constexpr (QKV) {
          if (nb < 1024) {               // Q: split hi/lo, uint2-packed
            u16 h0 = bf16rne(v0), h1 = bf16rne(v1);
            u16 h2 = bf16rne(v2), h3 = bf16rne(v3);
            *(uint2*)&Qhi[(size_t)m * 1024 + nb] =
                make_uint2((u32)h0 | ((u32)h1 << 16), (u32)h2 | ((u32)h3 << 16));
            u16 l0 = bf16rne(v0 - bf16tof(h0)), l1 = bf16rne(v1 - bf16tof(h1));
            u16 l2 = bf16rne(v2 - bf16tof(h2)), l3 = bf16rne(v3 - bf16tof(h3));
            *(uint2*)&Qlo[(size_t)m * 1024 + nb] =
                make_uint2((u32)l0 | ((u32)l1 << 16), (u32)l2 | ((u32)l3 << 16));
          } else if (nb < 2048) {        // K: hi bf16, uint2-packed
            *(uint2*)&Khi[(size_t)m * 1024 + (nb - 1024)] =
                make_uint2((u32)bf16rne(v0) | ((u32)bf16rne(v1) << 16),
                           (u32)bf16rne(v2) | ((u32)bf16rne(v3) << 16));
          } else {                       // V: transposed; contiguous in m
            Vt[(size_t)(nb - 2048 + 0) * 4096 + m] = bf16rne(v0);
            Vt[(size_t)(nb - 2048 + 1) * 4096 + m] = bf16rne(v1);
            Vt[(size_t)(nb - 2048 + 2) * 4096 + m] = bf16rne(v2);
            Vt[(size_t)(nb - 2048 + 3) * 4096 + m] = bf16rne(v3);
          }
        } else {
          float4 o; o.x = v0; o.y = v1; o.z = v2; o.w = v3;
          *(float4*)&C[(size_t)m * ldc + nb] = o;
        }
      }
    }
  }
}

// ---------------------------------------------------------------------------
// MFMA flash attention. grid = B*H*(T/64) = 1024 blocks, 256 thr (4 waves).
// S via mfma(Kh, Qhi/Qlo): D[k][q], q = l15. PV swapped: mfma(V, P) ->
// O[d][q=l15], lane-local rescale. Epilogue writes out_pre hi bf16 only
// (Wo GEMM is 1-pass).
// ---------------------------------------------------------------------------
__global__ __launch_bounds__(256) void attn_fused_mfma(
    const u16* __restrict__ Qhi, const u16* __restrict__ Qlo,
    const u16* __restrict__ Khi, const u16* __restrict__ Vt,
    float* __restrict__ mrow, float* __restrict__ linv,
    u16* __restrict__ ophi) {
  __shared__ u16 Kh_s[64][72];
  __shared__ u16 Vt_s[64][72];
  __shared__ u16 P_s[4][16][72];
  const int bi = blockIdx.x;
  const int qt = bi & 15, h = (bi >> 4) & 15, b = bi >> 8;
  const int tid = threadIdx.x;
  const int lane = tid & 63, w = tid >> 6;
  const int l15 = lane & 15, g = lane >> 4;
  const int q0 = qt * 64 + w * 16;
  const float scale = 0.125f;
  bf16x8 qh[2], ql[2];
  {
    size_t qoff = (size_t)(b * T_ + q0 + l15) * 1024 + h * DH_;
    qh[0] = *(const bf16x8*)&Qhi[qoff + 8 * g];
    qh[1] = *(const bf16x8*)&Qhi[qoff + 32 + 8 * g];
    ql[0] = *(const bf16x8*)&Qlo[qoff + 8 * g];
    ql[1] = *(const bf16x8*)&Qlo[qoff + 32 + 8 * g];
  }
  float m_run = -1e30f, l_run = 0.f;
  f32x4 acc_o[4];
#pragma unroll
  for (int nf = 0; nf < 4; nf++) {
    acc_o[nf][0] = 0.f; acc_o[nf][1] = 0.f; acc_o[nf][2] = 0.f; acc_o[nf][3] = 0.f;
  }

#pragma unroll 1
  for (int kt = 0; kt < 16; kt++) {
    {
      int r = tid >> 2, cs = (tid & 3) * 16;
      size_t krow = (size_t)(b * T_ + kt * 64 + r) * 1024 + h * DH_ + cs;
      *(uint4*)&Kh_s[r][cs]     = *(const uint4*)&Khi[krow];
      *(uint4*)&Kh_s[r][cs + 8] = *(const uint4*)&Khi[krow + 8];
      size_t vrow = (size_t)r * 4096 + b * T_ + kt * 64 + cs;
      *(uint4*)&Vt_s[r][cs]     = *(const uint4*)&Vt[vrow];
      *(uint4*)&Vt_s[r][cs + 8] = *(const uint4*)&Vt[vrow + 8];
    }
    __syncthreads();
    f32x4 accs[4];
#pragma unroll
    for (int mf = 0; mf < 4; mf++) {
      accs[mf][0] = 0.f; accs[mf][1] = 0.f; accs[mf][2] = 0.f; accs[mf][3] = 0.f;
    }
#pragma unroll
    for (int mf = 0; mf < 4; mf++) {
#pragma unroll
      for (int ks = 0; ks < 2; ks++) {
        bf16x8 kh = *(bf16x8*)&Kh_s[mf * 16 + l15][ks * 32 + 8 * g];
        accs[mf] = __builtin_amdgcn_mfma_f32_16x16x32_bf16(kh, qh[ks], accs[mf], 0, 0, 0);
        accs[mf] = __builtin_amdgcn_mfma_f32_16x16x32_bf16(kh, ql[ks], accs[mf], 0, 0, 0);
      }
    }
    float tm = -1e30f;
#pragma unroll
    for (int mf = 0; mf < 4; mf++)
#pragma unroll
      for (int r = 0; r < 4; r++) {
        accs[mf][r] *= scale;
        tm = fmaxf(tm, accs[mf][r]);
      }
    tm = fmaxf(tm, __shfl_xor(tm, 16));
    tm = fmaxf(tm, __shfl_xor(tm, 32));
    float m_new = fmaxf(m_run, tm);
    float crs = __expf(m_run - m_new);
    float ts = 0.f;
#pragma unroll
    for (int mf = 0; mf < 4; mf++) {
      float p0 = __expf(accs[mf][0] - m_new);
      float p1 = __expf(accs[mf][1] - m_new);
      float p2 = __expf(accs[mf][2] - m_new);
      float p3 = __expf(accs[mf][3] - m_new);
      ts += (p0 + p1) + (p2 + p3);
      u32 w0 = (u32)bf16rne(p0) | ((u32)bf16rne(p1) << 16);
      u32 w1 = (u32)bf16rne(p2) | ((u32)bf16rne(p3) << 16);
      *(uint2*)&P_s[w][l15][16 * mf + 4 * g] = make_uint2(w0, w1);
    }
    ts += __shfl_xor(ts, 16);
    ts += __shfl_xor(ts, 32);
    l_run = l_run * crs + ts;
    m_run = m_new;
    __syncthreads();
    // PV (swapped): O[d][q=l15]; rescale by lane-local crs
#pragma unroll
    for (int nf = 0; nf < 4; nf++)
#pragma unroll
      for (int r = 0; r < 4; r++) acc_o[nf][r] *= crs;
    bf16x8 pa[2];
    pa[0] = *(bf16x8*)&P_s[w][l15][8 * g];
    pa[1] = *(bf16x8*)&P_s[w][l15][32 + 8 * g];
#pragma unroll
    for (int nf = 0; nf < 4; nf++) {
#pragma unroll
      for (int ks = 0; ks < 2; ks++) {
        bf16x8 vb = *(bf16x8*)&Vt_s[nf * 16 + l15][ks * 32 + 8 * g];
        acc_o[nf] = __builtin_amdgcn_mfma_f32_16x16x32_bf16(vb, pa[ks], acc_o[nf], 0, 0, 0);
      }
    }
    __syncthreads();
  }
  float li = 1.0f / l_run;
  if (g == 0) {
    int idx = (b * H_ + h) * T_ + q0 + l15;
    mrow[idx] = m_run;
    linv[idx] = li;
  }
  // out: d = nf*16 + 4g + r (4 consecutive), q = l15 -> uint2-packed stores
  size_t obase = (size_t)(b * T_ + q0 + l15) * D_ + h * DH_;
#pragma unroll
  for (int nf = 0; nf < 4; nf++) {
    float v0 = acc_o[nf][0] * li, v1 = acc_o[nf][1] * li;
    float v2 = acc_o[nf][2] * li, v3 = acc_o[nf][3] * li;
    *(uint2*)&ophi[obase + nf * 16 + 4 * g] =
        make_uint2((u32)bf16rne(v0) | ((u32)bf16rne(v1) << 16),
                   (u32)bf16rne(v2) | ((u32)bf16rne(v3) << 16));
  }
}

// ---------------------------------------------------------------------------
// MFMA attn_mean. grid = B*(T/64)*(T/64) = 1024 blocks. 1-pass S (Qhi only).
// ---------------------------------------------------------------------------
__global__ __launch_bounds__(256) void attn_mean_mfma(
    const u16* __restrict__ Qhi, const u16* __restrict__ Khi,
    const float* __restrict__ mrow, const float* __restrict__ linv,
    float* __restrict__ am_out) {
  __shared__ u16 Kh_s[64][72];
  const int bi = blockIdx.x;
  const int kc = bi & 15, qt = (bi >> 4) & 15, b = bi >> 8;
  const int tid = threadIdx.x;
  const int lane = tid & 63, w = tid >> 6;
  const int l15 = lane & 15, g = lane >> 4;
  const int q0 = qt * 64 + w * 16, k0 = kc * 64;
  const float scale = 0.125f;
  float am[4][4] = {};
#pragma unroll 1
  for (int h = 0; h < H_; h++) {
    {
      int r = tid >> 2, cs = (tid & 3) * 16;
      size_t krow = (size_t)(b * T_ + k0 + r) * 1024 + h * DH_ + cs;
      *(uint4*)&Kh_s[r][cs]     = *(const uint4*)&Khi[krow];
      *(uint4*)&Kh_s[r][cs + 8] = *(const uint4*)&Khi[krow + 8];
    }
    __syncthreads();
    bf16x8 qh[2];
    {
      size_t qoff = (size_t)(b * T_ + q0 + l15) * 1024 + h * DH_;
      qh[0] = *(const bf16x8*)&Qhi[qoff + 8 * g];
      qh[1] = *(const bf16x8*)&Qhi[qoff + 32 + 8 * g];
    }
    f32x4 accs[4];
#pragma unroll
    for (int mf = 0; mf < 4; mf++) {
      accs[mf][0] = 0.f; accs[mf][1] = 0.f; accs[mf][2] = 0.f; accs[mf][3] = 0.f;
    }
#pragma unroll
    for (int mf = 0; mf < 4; mf++) {
#pragma unroll
      for (int ks = 0; ks < 2; ks++) {
        bf16x8 kh = *(bf16x8*)&Kh_s[mf * 16 + l15][ks * 32 + 8 * g];
        accs[mf] = __builtin_amdgcn_mfma_f32_16x16x32_bf16(kh, qh[ks], accs[mf], 0, 0, 0);
      }
    }
    const float mq = mrow[(b * H_ + h) * T_ + q0 + l15];
    const float li = linv[(b * H_ + h) * T_ + q0 + l15];
#pragma unroll
    for (int mf = 0; mf < 4; mf++)
#pragma unroll
      for (int r = 0; r < 4; r++)
        am[mf][r] += __expf(accs[mf][r] * scale - mq) * li;
    __syncthreads();
  }
  const float inv16 = 1.0f / 16.0f;
#pragma unroll
  for (int mf = 0; mf < 4; mf++) {
    float4 o;
    o.x = am[mf][0] * inv16; o.y = am[mf][1] * inv16;
    o.z = am[mf][2] * inv16; o.w = am[mf][3] * inv16;
    *(float4*)&am_out[(size_t)(b * T_ + q0 + l15) * T_ + k0 + 16 * mf + 4 * g] = o;
  }
}

// ---------------------------------------------------------------------------
extern "C" void kernel_launch(void* const* d_in, const int* in_sizes, int n_in,
                              void* d_out, int out_size, void* d_ws, size_t ws_size,
                              hipStream_t stream) {
  const float* x  = (const float*)d_in[0];
  const float* Wq = (const float*)d_in[1];
  const float* bq = (const float*)d_in[2];
  const float* Wk = (const float*)d_in[3];
  const float* bk = (const float*)d_in[4];
  const float* Wv = (const float*)d_in[5];
  const float* bv = (const float*)d_in[6];
  const float* Wo = (const float*)d_in[7];
  const float* bo = (const float*)d_in[8];

  float* out = (float*)d_out;                      // [B,T,D]
  float* am  = out + (size_t)B_ * T_ * D_;         // [B,T,T]

  char* w = (char*)d_ws;
  u16* Qhi   = (u16*)w; w += (size_t)4096 * 1024 * 2;
  u16* Qlo   = (u16*)w; w += (size_t)4096 * 1024 * 2;
  u16* Khi   = (u16*)w; w += (size_t)4096 * 1024 * 2;
  u16* Vt    = (u16*)w; w += (size_t)64 * 4096 * 2;
  u16* xhi   = (u16*)w; w += (size_t)4096 * 1024 * 2;  // x-hi, then out_pre hi
  u16* WcThi = (u16*)w; w += (size_t)NCAT * 1024 * 2;
  u16* WcTlo = (u16*)w; w += (size_t)NCAT * 1024 * 2;
  u16* WoThi = (u16*)w; w += (size_t)1024 * 1024 * 2;
  float* mrow  = (float*)w; w += (size_t)B_ * H_ * T_ * 4;
  float* linvp = (float*)w; w += (size_t)B_ * H_ * T_ * 4;
  float* bcat  = (float*)w; w += (size_t)NCAT * 4;

  wprep<<<785, 256, 0, stream>>>(Wq, Wk, Wv, Wo, bq, bk, bv,
                                 WcThi, WcTlo, WoThi, bcat);
  rowconv<<<2048, 256, 0, stream>>>(x, xhi);

  // QKV GEMM (2-pass: x_hi @ (W_hi + W_lo)) -> Qhi/Qlo, Khi, Vt
  mfma_gemm<128, true><<<dim3(32, 17), 256, 0, stream>>>(
      xhi, WcThi, WcTlo, bcat, nullptr, NCAT, 1024, 0,
      Qhi, Qlo, Khi, Vt);

  attn_fused_mfma<<<1024, 256, 0, stream>>>(Qhi, Qlo, Khi, Vt,
                                            mrow, linvp, xhi);
  attn_mean_mfma<<<1024, 256, 0, stream>>>(Qhi, Khi, mrow, linvp, am);

  // Wo GEMM (1-pass bf16)
  mfma_gemm<64, false><<<dim3(64, 8), 256, 0, stream>>>(
      xhi, WoThi, nullptr, bo, out, 1024, 1024, 1024,
      nullptr, nullptr, nullptr, nullptr);
}

// Round 11
// 158.790 us; speedup vs baseline: 1.4803x; 1.0979x over previous
//
#include <hip/hip_runtime.h>
#include <math.h>

#define B_ 4
#define T_ 1024
#define D_ 1024
#define H_ 16
#define DH_ 64
#define NCAT 2112   // 1024 (Q) + 1024 (K) + 64 (V)

typedef unsigned short u16;
typedef unsigned int u32;
typedef __attribute__((ext_vector_type(8))) short bf16x8;
typedef __attribute__((ext_vector_type(4))) float f32x4;

__device__ __forceinline__ u16 bf16rne(float f) {
  u32 u = __float_as_uint(f);
  u32 r = (u + 0x7fffu + ((u >> 16) & 1u)) >> 16;
  return (u16)r;
}
__device__ __forceinline__ float bf16tof(u16 h) {
  return __uint_as_float((u32)h << 16);
}

// async global->LDS, 16B per lane; LDS dest = wave-uniform base + lane*16
__device__ __forceinline__ void gload_lds16(const u16* g, u16* l) {
  __builtin_amdgcn_global_load_lds(
      (const __attribute__((address_space(1))) unsigned int*)g,
      (__attribute__((address_space(3))) unsigned int*)l, 16, 0, 0);
}

// ---------------------------------------------------------------------------
// wprep: weight transposes + bf16 round (hi only; all GEMMs 1-pass in W)
// + bias concat, in ONE launch.
// blocks 0..255: Wq; 256..511: Wk; 512..767: Wo; 768..783: Wv; 784: biases.
// ---------------------------------------------------------------------------
__global__ __launch_bounds__(256) void wprep(
    const float* __restrict__ Wq, const float* __restrict__ Wk,
    const float* __restrict__ Wv, const float* __restrict__ Wo,
    const float* __restrict__ bq, const float* __restrict__ bk,
    const float* __restrict__ bv,
    u16* __restrict__ WcThi, u16* __restrict__ WoThi,
    float* __restrict__ bcat) {
  const int blk = blockIdx.x;
  if (blk == 784) {
    for (int i = threadIdx.x; i < NCAT; i += 256)
      bcat[i] = (i < 1024) ? bq[i] : ((i < 2048) ? bk[i - 1024] : bv[i - 2048]);
    return;
  }
  const float* W;
  u16* Thi;
  int roff, Nw, bx, by;
  if (blk < 256)      { W = Wq; Thi = WcThi; roff = 0;    Nw = 1024; bx = blk & 15;         by = blk >> 4; }
  else if (blk < 512) { W = Wk; Thi = WcThi; roff = 1024; Nw = 1024; bx = (blk - 256) & 15; by = (blk - 256) >> 4; }
  else if (blk < 768) { W = Wo; Thi = WoThi; roff = 0;    Nw = 1024; bx = (blk - 512) & 15; by = (blk - 512) >> 4; }
  else                { W = Wv; Thi = WcThi; roff = 2048; Nw = 64;   bx = 0;                by = blk - 768; }

  __shared__ float Ws[64][65];
  const int t = threadIdx.x;
  const int n0 = bx * 64, k0 = by * 64;
#pragma unroll
  for (int rr = 0; rr < 4; rr++) {
    int r = rr * 16 + (t >> 4);
    int c = (t & 15) * 4;
    float4 v = *(const float4*)&W[(size_t)(k0 + r) * Nw + n0 + c];
    Ws[r][c] = v.x; Ws[r][c + 1] = v.y; Ws[r][c + 2] = v.z; Ws[r][c + 3] = v.w;
  }
  __syncthreads();
  const int n = t >> 2, kc = t & 3;
  u32 uh[8];
#pragma unroll
  for (int j2 = 0; j2 < 8; j2++) {
    u16 h0 = bf16rne(Ws[kc * 16 + j2 * 2 + 0][n]);
    u16 h1 = bf16rne(Ws[kc * 16 + j2 * 2 + 1][n]);
    uh[j2] = (u32)h0 | ((u32)h1 << 16);
  }
  size_t base = (size_t)(roff + n0 + n) * 1024 + k0 + kc * 16;
  *(uint4*)&Thi[base]     = make_uint4(uh[0], uh[1], uh[2], uh[3]);
  *(uint4*)&Thi[base + 8] = make_uint4(uh[4], uh[5], uh[6], uh[7]);
}

// ---------------------------------------------------------------------------
// Row-major bf16 round: in fp32 [4096*1024] -> hi bf16, same layout.
// ---------------------------------------------------------------------------
__global__ __launch_bounds__(256) void rowconv(
    const float* __restrict__ in, u16* __restrict__ hi) {
  size_t i = ((size_t)blockIdx.x * 256 + threadIdx.x) * 8;
  float4 v0 = *(const float4*)&in[i];
  float4 v1 = *(const float4*)&in[i + 4];
  float vv[8] = {v0.x, v0.y, v0.z, v0.w, v1.x, v1.y, v1.z, v1.w};
  u32 uh[4];
#pragma unroll
  for (int j = 0; j < 4; j++) {
    uh[j] = (u32)bf16rne(vv[2 * j]) | ((u32)bf16rne(vv[2 * j + 1]) << 16);
  }
  *(uint4*)&hi[i] = make_uint4(uh[0], uh[1], uh[2], uh[3]);
}

// ---------------------------------------------------------------------------
// bf16 MFMA GEMM, 1-pass, m97-style staging (global_load_lds 16B, linear
// LDS), TM x 128 tile, BK=32, 4 waves (2x2). MFMA operands SWAPPED:
// mfma(B,A) -> D[n][m]: thread holds 4 consecutive n at fixed m.
// QKV=true epilogue: Q -> split hi/lo | K -> hi | V -> transposed bf16.
// QKV=false: fp32 C + bias (Wo projection).
// ---------------------------------------------------------------------------
template <int TM, bool QKV>
__global__ __launch_bounds__(256) void mfma_gemm(
    const u16* __restrict__ Ahi, const u16* __restrict__ Bhi,
    const float* __restrict__ bias, float* __restrict__ C,
    int Nvalid, int Kd, int ldc,
    u16* __restrict__ Qhi, u16* __restrict__ Qlo,
    u16* __restrict__ Khi, u16* __restrict__ Vt) {
  constexpr int MF = TM / 32;   // M-fragments per wave
  constexpr int AC = TM / 64;   // A 1KB-chunks per wave
  __shared__ u16 Ah[TM][32];
  __shared__ u16 Bh[128][32];
  const int tid = threadIdx.x;
  const int lane = tid & 63, wid = tid >> 6;
  const int wr = wid >> 1, wc = wid & 1;
  const int m0 = blockIdx.x * TM, n0 = blockIdx.y * 128;
  f32x4 acc[MF][4];
#pragma unroll
  for (int i = 0; i < MF; i++)
#pragma unroll
    for (int j = 0; j < 4; j++) {
      acc[i][j][0] = 0.f; acc[i][j][1] = 0.f;
      acc[i][j][2] = 0.f; acc[i][j][3] = 0.f;
    }
  const int fo = 8 * (lane >> 4);
  const int fr = lane & 15;
  const int srow = lane >> 2;        // row within a 16-row chunk
  const int scol = (lane & 3) * 8;   // u16 col within BK=32

#pragma unroll 1
  for (int k0 = 0; k0 < Kd; k0 += 32) {
#pragma unroll
    for (int c = 0; c < AC; c++) {
      int chunk = wid * AC + c;
      size_t ga = (size_t)(m0 + chunk * 16 + srow) * Kd + k0 + scol;
      gload_lds16(&Ahi[ga], ((u16*)Ah) + chunk * 512);
    }
#pragma unroll
    for (int c = 0; c < 2; c++) {
      int chunk = wid * 2 + c;
      int grow = n0 + chunk * 16 + srow;
      if (grow >= Nvalid) grow = Nvalid - 1;  // clamp; epilogue masks
      size_t gb = (size_t)grow * Kd + k0 + scol;
      gload_lds16(&Bhi[gb], ((u16*)Bh) + chunk * 512);
    }
    __syncthreads();
    bf16x8 bhf[4];
#pragma unroll
    for (int nf = 0; nf < 4; nf++) {
      int r = wc * 64 + nf * 16 + fr;
      bhf[nf] = *(bf16x8*)&Bh[r][fo];
    }
#pragma unroll
    for (int mf = 0; mf < MF; mf++) {
      int r = wr * (TM / 2) + mf * 16 + fr;
      bf16x8 ahf = *(bf16x8*)&Ah[r][fo];
#pragma unroll
      for (int nf = 0; nf < 4; nf++)
        acc[mf][nf] = __builtin_amdgcn_mfma_f32_16x16x32_bf16(bhf[nf], ahf, acc[mf][nf], 0, 0, 0);
    }
    __syncthreads();
  }
  // D transposed: row(4*rq+r) = n within nf-tile, col(fr) = m within mf-tile
  const int rq = lane >> 4;
#pragma unroll
  for (int mf = 0; mf < MF; mf++) {
    int m = m0 + wr * (TM / 2) + mf * 16 + fr;
#pragma unroll
    for (int nf = 0; nf < 4; nf++) {
      int nb = n0 + wc * 64 + nf * 16 + rq * 4;
      if (nb < Nvalid) {
        float4 b4 = *(const float4*)&bias[nb];
        float v0 = acc[mf][nf][0] + b4.x;
        float v1 = acc[mf][nf][1] + b4.y;
        float v2 = acc[mf][nf][2] + b4.z;
        float v3 = acc[mf][nf][3] + b4.w;
        if constexpr (QKV) {
          if (nb < 1024) {               // Q: split hi/lo, uint2-packed
            u16 h0 = bf16rne(v0), h1 = bf16rne(v1);
            u16 h2 = bf16rne(v2), h3 = bf16rne(v3);
            *(uint2*)&Qhi[(size_t)m * 1024 + nb] =
                make_uint2((u32)h0 | ((u32)h1 << 16), (u32)h2 | ((u32)h3 << 16));
            u16 l0 = bf16rne(v0 - bf16tof(h0)), l1 = bf16rne(v1 - bf16tof(h1));
            u16 l2 = bf16rne(v2 - bf16tof(h2)), l3 = bf16rne(v3 - bf16tof(h3));
            *(uint2*)&Qlo[(size_t)m * 1024 + nb] =
                make_uint2((u32)l0 | ((u32)l1 << 16), (u32)l2 | ((u32)l3 << 16));
          } else if (nb < 2048) {        // K: hi bf16, uint2-packed
            *(uint2*)&Khi[(size_t)m * 1024 + (nb - 1024)] =
                make_uint2((u32)bf16rne(v0) | ((u32)bf16rne(v1) << 16),
                           (u32)bf16rne(v2) | ((u32)bf16rne(v3) << 16));
          } else {                       // V: transposed; contiguous in m
            Vt[(size_t)(nb - 2048 + 0) * 4096 + m] = bf16rne(v0);
            Vt[(size_t)(nb - 2048 + 1) * 4096 + m] = bf16rne(v1);
            Vt[(size_t)(nb - 2048 + 2) * 4096 + m] = bf16rne(v2);
            Vt[(size_t)(nb - 2048 + 3) * 4096 + m] = bf16rne(v3);
          }
        } else {
          float4 o; o.x = v0; o.y = v1; o.z = v2; o.w = v3;
          *(float4*)&C[(size_t)m * ldc + nb] = o;
        }
      }
    }
  }
}

// ---------------------------------------------------------------------------
// MFMA flash attention. grid = B*H*(T/64) = 1024 blocks, 256 thr (4 waves).
// S via mfma(Kh, Qhi/Qlo): D[k][q], q = l15. PV swapped: mfma(V, P) ->
// O[d][q=l15], lane-local rescale. One barrier per kt (P_s is wave-private;
// DS ops are wave-ordered, alias analysis on P_s preserves write->read order).
// ---------------------------------------------------------------------------
__global__ __launch_bounds__(256) void attn_fused_mfma(
    const u16* __restrict__ Qhi, const u16* __restrict__ Qlo,
    const u16* __restrict__ Khi, const u16* __restrict__ Vt,
    float* __restrict__ mrow, float* __restrict__ linv,
    u16* __restrict__ ophi) {
  __shared__ u16 Kh_s[64][72];
  __shared__ u16 Vt_s[64][72];
  __shared__ u16 P_s[4][16][72];
  const int bi = blockIdx.x;
  const int qt = bi & 15, h = (bi >> 4) & 15, b = bi >> 8;
  const int tid = threadIdx.x;
  const int lane = tid & 63, w = tid >> 6;
  const int l15 = lane & 15, g = lane >> 4;
  const int q0 = qt * 64 + w * 16;
  const float scale = 0.125f;
  bf16x8 qh[2], ql[2];
  {
    size_t qoff = (size_t)(b * T_ + q0 + l15) * 1024 + h * DH_;
    qh[0] = *(const bf16x8*)&Qhi[qoff + 8 * g];
    qh[1] = *(const bf16x8*)&Qhi[qoff + 32 + 8 * g];
    ql[0] = *(const bf16x8*)&Qlo[qoff + 8 * g];
    ql[1] = *(const bf16x8*)&Qlo[qoff + 32 + 8 * g];
  }
  float m_run = -1e30f, l_run = 0.f;
  f32x4 acc_o[4];
#pragma unroll
  for (int nf = 0; nf < 4; nf++) {
    acc_o[nf][0] = 0.f; acc_o[nf][1] = 0.f; acc_o[nf][2] = 0.f; acc_o[nf][3] = 0.f;
  }

#pragma unroll 1
  for (int kt = 0; kt < 16; kt++) {
    {
      int r = tid >> 2, cs = (tid & 3) * 16;
      size_t krow = (size_t)(b * T_ + kt * 64 + r) * 1024 + h * DH_ + cs;
      *(uint4*)&Kh_s[r][cs]     = *(const uint4*)&Khi[krow];
      *(uint4*)&Kh_s[r][cs + 8] = *(const uint4*)&Khi[krow + 8];
      size_t vrow = (size_t)r * 4096 + b * T_ + kt * 64 + cs;
      *(uint4*)&Vt_s[r][cs]     = *(const uint4*)&Vt[vrow];
      *(uint4*)&Vt_s[r][cs + 8] = *(const uint4*)&Vt[vrow + 8];
    }
    __syncthreads();
    f32x4 accs[4];
#pragma unroll
    for (int mf = 0; mf < 4; mf++) {
      accs[mf][0] = 0.f; accs[mf][1] = 0.f; accs[mf][2] = 0.f; accs[mf][3] = 0.f;
    }
#pragma unroll
    for (int mf = 0; mf < 4; mf++) {
#pragma unroll
      for (int ks = 0; ks < 2; ks++) {
        bf16x8 kh = *(bf16x8*)&Kh_s[mf * 16 + l15][ks * 32 + 8 * g];
        accs[mf] = __builtin_amdgcn_mfma_f32_16x16x32_bf16(kh, qh[ks], accs[mf], 0, 0, 0);
        accs[mf] = __builtin_amdgcn_mfma_f32_16x16x32_bf16(kh, ql[ks], accs[mf], 0, 0, 0);
      }
    }
    float tm = -1e30f;
#pragma unroll
    for (int mf = 0; mf < 4; mf++)
#pragma unroll
      for (int r = 0; r < 4; r++) {
        accs[mf][r] *= scale;
        tm = fmaxf(tm, accs[mf][r]);
      }
    tm = fmaxf(tm, __shfl_xor(tm, 16));
    tm = fmaxf(tm, __shfl_xor(tm, 32));
    float m_new = fmaxf(m_run, tm);
    float crs = __expf(m_run - m_new);
    float ts = 0.f;
#pragma unroll
    for (int mf = 0; mf < 4; mf++) {
      float p0 = __expf(accs[mf][0] - m_new);
      float p1 = __expf(accs[mf][1] - m_new);
      float p2 = __expf(accs[mf][2] - m_new);
      float p3 = __expf(accs[mf][3] - m_new);
      ts += (p0 + p1) + (p2 + p3);
      u32 w0 = (u32)bf16rne(p0) | ((u32)bf16rne(p1) << 16);
      u32 w1 = (u32)bf16rne(p2) | ((u32)bf16rne(p3) << 16);
      *(uint2*)&P_s[w][l15][16 * mf + 4 * g] = make_uint2(w0, w1);
    }
    ts += __shfl_xor(ts, 16);
    ts += __shfl_xor(ts, 32);
    l_run = l_run * crs + ts;
    m_run = m_new;
    // PV (swapped): O[d][q=l15]; rescale by lane-local crs.
    // No block barrier needed: P_s slice is wave-private.
#pragma unroll
    for (int nf = 0; nf < 4; nf++)
#pragma unroll
      for (int r = 0; r < 4; r++) acc_o[nf][r] *= crs;
    bf16x8 pa[2];
    pa[0] = *(bf16x8*)&P_s[w][l15][8 * g];
    pa[1] = *(bf16x8*)&P_s[w][l15][32 + 8 * g];
#pragma unroll
    for (int nf = 0; nf < 4; nf++) {
#pragma unroll
      for (int ks = 0; ks < 2; ks++) {
        bf16x8 vb = *(bf16x8*)&Vt_s[nf * 16 + l15][ks * 32 + 8 * g];
        acc_o[nf] = __builtin_amdgcn_mfma_f32_16x16x32_bf16(vb, pa[ks], acc_o[nf], 0, 0, 0);
      }
    }
    __syncthreads();
  }
  float li = 1.0f / l_run;
  if (g == 0) {
    int idx = (b * H_ + h) * T_ + q0 + l15;
    mrow[idx] = m_run;
    linv[idx] = li;
  }
  // out: d = nf*16 + 4g + r (4 consecutive), q = l15 -> uint2-packed stores
  size_t obase = (size_t)(b * T_ + q0 + l15) * D_ + h * DH_;
#pragma unroll
  for (int nf = 0; nf < 4; nf++) {
    float v0 = acc_o[nf][0] * li, v1 = acc_o[nf][1] * li;
    float v2 = acc_o[nf][2] * li, v3 = acc_o[nf][3] * li;
    *(uint2*)&ophi[obase + nf * 16 + 4 * g] =
        make_uint2((u32)bf16rne(v0) | ((u32)bf16rne(v1) << 16),
                   (u32)bf16rne(v2) | ((u32)bf16rne(v3) << 16));
  }
}

// ---------------------------------------------------------------------------
// MFMA attn_mean. grid = B*(T/64)*(T/64) = 1024 blocks. 1-pass S (Qhi only).
// ---------------------------------------------------------------------------
__global__ __launch_bounds__(256) void attn_mean_mfma(
    const u16* __restrict__ Qhi, const u16* __restrict__ Khi,
    const float* __restrict__ mrow, const float* __restrict__ linv,
    float* __restrict__ am_out) {
  __shared__ u16 Kh_s[64][72];
  const int bi = blockIdx.x;
  const int kc = bi & 15, qt = (bi >> 4) & 15, b = bi >> 8;
  const int tid = threadIdx.x;
  const int lane = tid & 63, w = tid >> 6;
  const int l15 = lane & 15, g = lane >> 4;
  const int q0 = qt * 64 + w * 16, k0 = kc * 64;
  const float scale = 0.125f;
  float am[4][4] = {};
#pragma unroll 1
  for (int h = 0; h < H_; h++) {
    {
      int r = tid >> 2, cs = (tid & 3) * 16;
      size_t krow = (size_t)(b * T_ + k0 + r) * 1024 + h * DH_ + cs;
      *(uint4*)&Kh_s[r][cs]     = *(const uint4*)&Khi[krow];
      *(uint4*)&Kh_s[r][cs + 8] = *(const uint4*)&Khi[krow + 8];
    }
    __syncthreads();
    bf16x8 qh[2];
    {
      size_t qoff = (size_t)(b * T_ + q0 + l15) * 1024 + h * DH_;
      qh[0] = *(const bf16x8*)&Qhi[qoff + 8 * g];
      qh[1] = *(const bf16x8*)&Qhi[qoff + 32 + 8 * g];
    }
    f32x4 accs[4];
#pragma unroll
    for (int mf = 0; mf < 4; mf++) {
      accs[mf][0] = 0.f; accs[mf][1] = 0.f; accs[mf][2] = 0.f; accs[mf][3] = 0.f;
    }
#pragma unroll
    for (int mf = 0; mf < 4; mf++) {
#pragma unroll
      for (int ks = 0; ks < 2; ks++) {
        bf16x8 kh = *(bf16x8*)&Kh_s[mf * 16 + l15][ks * 32 + 8 * g];
        accs[mf] = __builtin_amdgcn_mfma_f32_16x16x32_bf16(kh, qh[ks], accs[mf], 0, 0, 0);
      }
    }
    const float mq = mrow[(b * H_ + h) * T_ + q0 + l15];
    const float li = linv[(b * H_ + h) * T_ + q0 + l15];
#pragma unroll
    for (int mf = 0; mf < 4; mf++)
#pragma unroll
      for (int r = 0; r < 4; r++)
        am[mf][r] += __expf(accs[mf][r] * scale - mq) * li;
    __syncthreads();
  }
  const float inv16 = 1.0f / 16.0f;
#pragma unroll
  for (int mf = 0; mf < 4; mf++) {
    float4 o;
    o.x = am[mf][0] * inv16; o.y = am[mf][1] * inv16;
    o.z = am[mf][2] * inv16; o.w = am[mf][3] * inv16;
    *(float4*)&am_out[(size_t)(b * T_ + q0 + l15) * T_ + k0 + 16 * mf + 4 * g] = o;
  }
}

// ---------------------------------------------------------------------------
extern "C" void kernel_launch(void* const* d_in, const int* in_sizes, int n_in,
                              void* d_out, int out_size, void* d_ws, size_t ws_size,
                              hipStream_t stream) {
  const float* x  = (const float*)d_in[0];
  const float* Wq = (const float*)d_in[1];
  const float* bq = (const float*)d_in[2];
  const float* Wk = (const float*)d_in[3];
  const float* bk = (const float*)d_in[4];
  const float* Wv = (const float*)d_in[5];
  const float* bv = (const float*)d_in[6];
  const float* Wo = (const float*)d_in[7];
  const float* bo = (const float*)d_in[8];

  float* out = (float*)d_out;                      // [B,T,D]
  float* am  = out + (size_t)B_ * T_ * D_;         // [B,T,T]

  char* w = (char*)d_ws;
  u16* Qhi   = (u16*)w; w += (size_t)4096 * 1024 * 2;
  u16* Qlo   = (u16*)w; w += (size_t)4096 * 1024 * 2;
  u16* Khi   = (u16*)w; w += (size_t)4096 * 1024 * 2;
  u16* Vt    = (u16*)w; w += (size_t)64 * 4096 * 2;
  u16* xhi   = (u16*)w; w += (size_t)4096 * 1024 * 2;  // x-hi, then out_pre hi
  u16* WcThi = (u16*)w; w += (size_t)NCAT * 1024 * 2;
  u16* WoThi = (u16*)w; w += (size_t)1024 * 1024 * 2;
  float* mrow  = (float*)w; w += (size_t)B_ * H_ * T_ * 4;
  float* linvp = (float*)w; w += (size_t)B_ * H_ * T_ * 4;
  float* bcat  = (float*)w; w += (size_t)NCAT * 4;

  wprep<<<785, 256, 0, stream>>>(Wq, Wk, Wv, Wo, bq, bk, bv,
                                 WcThi, WoThi, bcat);
  rowconv<<<2048, 256, 0, stream>>>(x, xhi);

  // QKV GEMM (1-pass: x_hi @ W_hi) -> Qhi/Qlo, Khi, Vt
  mfma_gemm<128, true><<<dim3(32, 17), 256, 0, stream>>>(
      xhi, WcThi, bcat, nullptr, NCAT, 1024, 0, Qhi, Qlo, Khi, Vt);

  attn_fused_mfma<<<1024, 256, 0, stream>>>(Qhi, Qlo, Khi, Vt,
                                            mrow, linvp, xhi);
  attn_mean_mfma<<<1024, 256, 0, stream>>>(Qhi, Khi, mrow, linvp, am);

  // Wo GEMM (1-pass bf16)
  mfma_gemm<64, false><<<dim3(64, 8), 256, 0, stream>>>(
      xhi, WoThi, bo, out, 1024, 1024, 1024,
      nullptr, nullptr, nullptr, nullptr);
}

// Round 12
// 145.264 us; speedup vs baseline: 1.6182x; 1.0931x over previous
//
#include <hip/hip_runtime.h>
#include <math.h>

#define B_ 4
#define T_ 1024
#define D_ 1024
#define H_ 16
#define DH_ 64
#define NCAT 2112   // 1024 (Q) + 1024 (K) + 64 (V)

typedef unsigned short u16;
typedef unsigned int u32;
typedef __attribute__((ext_vector_type(8))) short bf16x8;
typedef __attribute__((ext_vector_type(4))) float f32x4;

// log2-domain score scale: DH^-0.5 * log2(e)
#define SCALE2 0.18033688f

__device__ __forceinline__ u16 bf16rne(float f) {
  u32 u = __float_as_uint(f);
  u32 r = (u + 0x7fffu + ((u >> 16) & 1u)) >> 16;
  return (u16)r;
}
__device__ __forceinline__ float bf16tof(u16 h) {
  return __uint_as_float((u32)h << 16);
}
// pack 2 f32 -> 2 bf16 in one instr (T12 recipe; P-pack only)
__device__ __forceinline__ u32 cvtpk(float lo, float hi) {
  u32 r;
  asm("v_cvt_pk_bf16_f32 %0, %1, %2" : "=v"(r) : "v"(lo), "v"(hi));
  return r;
}

// async global->LDS, 16B per lane; LDS dest = wave-uniform base + lane*16
__device__ __forceinline__ void gload_lds16(const u16* g, u16* l) {
  __builtin_amdgcn_global_load_lds(
      (const __attribute__((address_space(1))) unsigned int*)g,
      (__attribute__((address_space(3))) unsigned int*)l, 16, 0, 0);
}

// ---------------------------------------------------------------------------
// wprep: weight transposes + bf16 round (hi only) + bias concat, ONE launch.
// ---------------------------------------------------------------------------
__global__ __launch_bounds__(256) void wprep(
    const float* __restrict__ Wq, const float* __restrict__ Wk,
    const float* __restrict__ Wv, const float* __restrict__ Wo,
    const float* __restrict__ bq, const float* __restrict__ bk,
    const float* __restrict__ bv,
    u16* __restrict__ WcThi, u16* __restrict__ WoThi,
    float* __restrict__ bcat) {
  const int blk = blockIdx.x;
  if (blk == 784) {
    for (int i = threadIdx.x; i < NCAT; i += 256)
      bcat[i] = (i < 1024) ? bq[i] : ((i < 2048) ? bk[i - 1024] : bv[i - 2048]);
    return;
  }
  const float* W;
  u16* Thi;
  int roff, Nw, bx, by;
  if (blk < 256)      { W = Wq; Thi = WcThi; roff = 0;    Nw = 1024; bx = blk & 15;         by = blk >> 4; }
  else if (blk < 512) { W = Wk; Thi = WcThi; roff = 1024; Nw = 1024; bx = (blk - 256) & 15; by = (blk - 256) >> 4; }
  else if (blk < 768) { W = Wo; Thi = WoThi; roff = 0;    Nw = 1024; bx = (blk - 512) & 15; by = (blk - 512) >> 4; }
  else                { W = Wv; Thi = WcThi; roff = 2048; Nw = 64;   bx = 0;                by = blk - 768; }

  __shared__ float Ws[64][65];
  const int t = threadIdx.x;
  const int n0 = bx * 64, k0 = by * 64;
#pragma unroll
  for (int rr = 0; rr < 4; rr++) {
    int r = rr * 16 + (t >> 4);
    int c = (t & 15) * 4;
    float4 v = *(const float4*)&W[(size_t)(k0 + r) * Nw + n0 + c];
    Ws[r][c] = v.x; Ws[r][c + 1] = v.y; Ws[r][c + 2] = v.z; Ws[r][c + 3] = v.w;
  }
  __syncthreads();
  const int n = t >> 2, kc = t & 3;
  u32 uh[8];
#pragma unroll
  for (int j2 = 0; j2 < 8; j2++) {
    u16 h0 = bf16rne(Ws[kc * 16 + j2 * 2 + 0][n]);
    u16 h1 = bf16rne(Ws[kc * 16 + j2 * 2 + 1][n]);
    uh[j2] = (u32)h0 | ((u32)h1 << 16);
  }
  size_t base = (size_t)(roff + n0 + n) * 1024 + k0 + kc * 16;
  *(uint4*)&Thi[base]     = make_uint4(uh[0], uh[1], uh[2], uh[3]);
  *(uint4*)&Thi[base + 8] = make_uint4(uh[4], uh[5], uh[6], uh[7]);
}

// ---------------------------------------------------------------------------
// Row-major bf16 round: in fp32 [4096*1024] -> hi bf16, same layout.
// ---------------------------------------------------------------------------
__global__ __launch_bounds__(256) void rowconv(
    const float* __restrict__ in, u16* __restrict__ hi) {
  size_t i = ((size_t)blockIdx.x * 256 + threadIdx.x) * 8;
  float4 v0 = *(const float4*)&in[i];
  float4 v1 = *(const float4*)&in[i + 4];
  float vv[8] = {v0.x, v0.y, v0.z, v0.w, v1.x, v1.y, v1.z, v1.w};
  u32 uh[4];
#pragma unroll
  for (int j = 0; j < 4; j++) {
    uh[j] = (u32)bf16rne(vv[2 * j]) | ((u32)bf16rne(vv[2 * j + 1]) << 16);
  }
  *(uint4*)&hi[i] = make_uint4(uh[0], uh[1], uh[2], uh[3]);
}

// ---------------------------------------------------------------------------
// bf16 MFMA GEMM, 1-pass, m97 staging (global_load_lds 16B, linear LDS),
// TM x 128 tile, BK=32, 4 waves (2x2). mfma(B,A) -> D[n][m]: 4 consecutive n
// at fixed m per thread. QKV=true: cols<2048 -> QK bf16 [m][2048]; cols>=2048
// -> Vt transposed bf16. QKV=false: fp32 C + bias.
// ---------------------------------------------------------------------------
template <int TM, bool QKV>
__global__ __launch_bounds__(256) void mfma_gemm(
    const u16* __restrict__ Ahi, const u16* __restrict__ Bhi,
    const float* __restrict__ bias, float* __restrict__ C,
    int Nvalid, int Kd, int ldc,
    u16* __restrict__ QK, u16* __restrict__ Vt) {
  constexpr int MF = TM / 32;   // M-fragments per wave
  constexpr int AC = TM / 64;   // A 1KB-chunks per wave
  __shared__ u16 Ah[TM][32];
  __shared__ u16 Bh[128][32];
  const int tid = threadIdx.x;
  const int lane = tid & 63, wid = tid >> 6;
  const int wr = wid >> 1, wc = wid & 1;
  const int m0 = blockIdx.x * TM, n0 = blockIdx.y * 128;
  f32x4 acc[MF][4];
#pragma unroll
  for (int i = 0; i < MF; i++)
#pragma unroll
    for (int j = 0; j < 4; j++) {
      acc[i][j][0] = 0.f; acc[i][j][1] = 0.f;
      acc[i][j][2] = 0.f; acc[i][j][3] = 0.f;
    }
  const int fo = 8 * (lane >> 4);
  const int fr = lane & 15;
  const int srow = lane >> 2;        // row within a 16-row chunk
  const int scol = (lane & 3) * 8;   // u16 col within BK=32

#pragma unroll 1
  for (int k0 = 0; k0 < Kd; k0 += 32) {
#pragma unroll
    for (int c = 0; c < AC; c++) {
      int chunk = wid * AC + c;
      size_t ga = (size_t)(m0 + chunk * 16 + srow) * Kd + k0 + scol;
      gload_lds16(&Ahi[ga], ((u16*)Ah) + chunk * 512);
    }
#pragma unroll
    for (int c = 0; c < 2; c++) {
      int chunk = wid * 2 + c;
      int grow = n0 + chunk * 16 + srow;
      if (grow >= Nvalid) grow = Nvalid - 1;  // clamp; epilogue masks
      size_t gb = (size_t)grow * Kd + k0 + scol;
      gload_lds16(&Bhi[gb], ((u16*)Bh) + chunk * 512);
    }
    __syncthreads();
    bf16x8 bhf[4];
#pragma unroll
    for (int nf = 0; nf < 4; nf++) {
      int r = wc * 64 + nf * 16 + fr;
      bhf[nf] = *(bf16x8*)&Bh[r][fo];
    }
#pragma unroll
    for (int mf = 0; mf < MF; mf++) {
      int r = wr * (TM / 2) + mf * 16 + fr;
      bf16x8 ahf = *(bf16x8*)&Ah[r][fo];
#pragma unroll
      for (int nf = 0; nf < 4; nf++)
        acc[mf][nf] = __builtin_amdgcn_mfma_f32_16x16x32_bf16(bhf[nf], ahf, acc[mf][nf], 0, 0, 0);
    }
    __syncthreads();
  }
  const int rq = lane >> 4;
#pragma unroll
  for (int mf = 0; mf < MF; mf++) {
    int m = m0 + wr * (TM / 2) + mf * 16 + fr;
#pragma unroll
    for (int nf = 0; nf < 4; nf++) {
      int nb = n0 + wc * 64 + nf * 16 + rq * 4;
      if (nb < Nvalid) {
        float4 b4 = *(const float4*)&bias[nb];
        float v0 = acc[mf][nf][0] + b4.x;
        float v1 = acc[mf][nf][1] + b4.y;
        float v2 = acc[mf][nf][2] + b4.z;
        float v3 = acc[mf][nf][3] + b4.w;
        if constexpr (QKV) {
          if (nb < 2048) {               // Q|K: bf16, uint2-packed
            *(uint2*)&QK[(size_t)m * 2048 + nb] =
                make_uint2((u32)bf16rne(v0) | ((u32)bf16rne(v1) << 16),
                           (u32)bf16rne(v2) | ((u32)bf16rne(v3) << 16));
          } else {                       // V: transposed; contiguous in m
            Vt[(size_t)(nb - 2048 + 0) * 4096 + m] = bf16rne(v0);
            Vt[(size_t)(nb - 2048 + 1) * 4096 + m] = bf16rne(v1);
            Vt[(size_t)(nb - 2048 + 2) * 4096 + m] = bf16rne(v2);
            Vt[(size_t)(nb - 2048 + 3) * 4096 + m] = bf16rne(v3);
          }
        } else {
          float4 o; o.x = v0; o.y = v1; o.z = v2; o.w = v3;
          *(float4*)&C[(size_t)m * ldc + nb] = o;
        }
      }
    }
  }
}

// ---------------------------------------------------------------------------
// MFMA flash attention. grid = 1024 blocks (XCD-swizzled), 4 waves.
// S via mfma(Kh, Qh) only (1-pass, log2 domain): D[k][q], q = l15.
// Defer-max (THR=8, log2): skip rescale unless some row max grew > 8.
// PV swapped: mfma(V, P) -> O[d][q=l15]. P packed via v_cvt_pk_bf16_f32.
// ---------------------------------------------------------------------------
__global__ __launch_bounds__(256) void attn_fused_mfma(
    const u16* __restrict__ QK, const u16* __restrict__ Vt,
    float* __restrict__ mrow, float* __restrict__ linv,
    u16* __restrict__ ophi) {
  __shared__ u16 Kh_s[64][72];
  __shared__ u16 Vt_s[64][72];
  __shared__ u16 P_s[4][16][72];
  const int bi0 = blockIdx.x;
  const int bi = (bi0 & 7) * 128 + (bi0 >> 3);  // XCD swizzle (1024 = 8*128)
  const int qt = bi & 15, h = (bi >> 4) & 15, b = bi >> 8;
  const int tid = threadIdx.x;
  const int lane = tid & 63, w = tid >> 6;
  const int l15 = lane & 15, g = lane >> 4;
  const int q0 = qt * 64 + w * 16;
  bf16x8 qh[2];
  {
    size_t qoff = (size_t)(b * T_ + q0 + l15) * 2048 + h * DH_;
    qh[0] = *(const bf16x8*)&QK[qoff + 8 * g];
    qh[1] = *(const bf16x8*)&QK[qoff + 32 + 8 * g];
  }
  float m_run = -1e30f, l_run = 0.f;
  f32x4 acc_o[4];
#pragma unroll
  for (int nf = 0; nf < 4; nf++) {
    acc_o[nf][0] = 0.f; acc_o[nf][1] = 0.f; acc_o[nf][2] = 0.f; acc_o[nf][3] = 0.f;
  }

#pragma unroll 1
  for (int kt = 0; kt < 16; kt++) {
    {
      int r = tid >> 2, cs = (tid & 3) * 16;
      size_t krow = (size_t)(b * T_ + kt * 64 + r) * 2048 + 1024 + h * DH_ + cs;
      *(uint4*)&Kh_s[r][cs]     = *(const uint4*)&QK[krow];
      *(uint4*)&Kh_s[r][cs + 8] = *(const uint4*)&QK[krow + 8];
      size_t vrow = (size_t)r * 4096 + b * T_ + kt * 64 + cs;
      *(uint4*)&Vt_s[r][cs]     = *(const uint4*)&Vt[vrow];
      *(uint4*)&Vt_s[r][cs + 8] = *(const uint4*)&Vt[vrow + 8];
    }
    __syncthreads();
    f32x4 accs[4];
#pragma unroll
    for (int mf = 0; mf < 4; mf++) {
      accs[mf][0] = 0.f; accs[mf][1] = 0.f; accs[mf][2] = 0.f; accs[mf][3] = 0.f;
    }
#pragma unroll
    for (int mf = 0; mf < 4; mf++) {
#pragma unroll
      for (int ks = 0; ks < 2; ks++) {
        bf16x8 kh = *(bf16x8*)&Kh_s[mf * 16 + l15][ks * 32 + 8 * g];
        accs[mf] = __builtin_amdgcn_mfma_f32_16x16x32_bf16(kh, qh[ks], accs[mf], 0, 0, 0);
      }
    }
    float tm = -1e30f;
#pragma unroll
    for (int mf = 0; mf < 4; mf++)
#pragma unroll
      for (int r = 0; r < 4; r++) {
        accs[mf][r] *= SCALE2;            // log2 domain
        tm = fmaxf(tm, accs[mf][r]);
      }
    tm = fmaxf(tm, __shfl_xor(tm, 16));
    tm = fmaxf(tm, __shfl_xor(tm, 32));
    // defer-max: only rescale when some row's max grew by > 8 (P <= 2^8)
    if (!__all(tm <= m_run + 8.f)) {
      float m_new = fmaxf(m_run, tm);
      float crs = __builtin_amdgcn_exp2f(m_run - m_new);
      l_run *= crs;
#pragma unroll
      for (int nf = 0; nf < 4; nf++)
#pragma unroll
        for (int r = 0; r < 4; r++) acc_o[nf][r] *= crs;
      m_run = m_new;
    }
    float ts = 0.f;
#pragma unroll
    for (int mf = 0; mf < 4; mf++) {
      float p0 = __builtin_amdgcn_exp2f(accs[mf][0] - m_run);
      float p1 = __builtin_amdgcn_exp2f(accs[mf][1] - m_run);
      float p2 = __builtin_amdgcn_exp2f(accs[mf][2] - m_run);
      float p3 = __builtin_amdgcn_exp2f(accs[mf][3] - m_run);
      ts += (p0 + p1) + (p2 + p3);
      *(uint2*)&P_s[w][l15][16 * mf + 4 * g] =
          make_uint2(cvtpk(p0, p1), cvtpk(p2, p3));
    }
    ts += __shfl_xor(ts, 16);
    ts += __shfl_xor(ts, 32);
    l_run += ts;
    // PV (swapped): O[d][q=l15]. P_s slice is wave-private; no block barrier.
    bf16x8 pa[2];
    pa[0] = *(bf16x8*)&P_s[w][l15][8 * g];
    pa[1] = *(bf16x8*)&P_s[w][l15][32 + 8 * g];
#pragma unroll
    for (int nf = 0; nf < 4; nf++) {
#pragma unroll
      for (int ks = 0; ks < 2; ks++) {
        bf16x8 vb = *(bf16x8*)&Vt_s[nf * 16 + l15][ks * 32 + 8 * g];
        acc_o[nf] = __builtin_amdgcn_mfma_f32_16x16x32_bf16(vb, pa[ks], acc_o[nf], 0, 0, 0);
      }
    }
    __syncthreads();
  }
  float li = 1.0f / l_run;
  if (g == 0) {
    int idx = (b * H_ + h) * T_ + q0 + l15;
    mrow[idx] = m_run;   // log2-domain deferred max; consistent with linv
    linv[idx] = li;
  }
  size_t obase = (size_t)(b * T_ + q0 + l15) * D_ + h * DH_;
#pragma unroll
  for (int nf = 0; nf < 4; nf++) {
    float v0 = acc_o[nf][0] * li, v1 = acc_o[nf][1] * li;
    float v2 = acc_o[nf][2] * li, v3 = acc_o[nf][3] * li;
    *(uint2*)&ophi[obase + nf * 16 + 4 * g] =
        make_uint2((u32)bf16rne(v0) | ((u32)bf16rne(v1) << 16),
                   (u32)bf16rne(v2) | ((u32)bf16rne(v3) << 16));
  }
}

// ---------------------------------------------------------------------------
// MFMA attn_mean. grid = 1024 (XCD-swizzled). 1-pass S, log2 domain —
// bit-identical S to attn_fused, so mrow/linv are exactly consistent.
// ---------------------------------------------------------------------------
__global__ __launch_bounds__(256) void attn_mean_mfma(
    const u16* __restrict__ QK, const float* __restrict__ mrow,
    const float* __restrict__ linv, float* __restrict__ am_out) {
  __shared__ u16 Kh_s[64][72];
  const int bi0 = blockIdx.x;
  const int bi = (bi0 & 7) * 128 + (bi0 >> 3);  // XCD swizzle
  const int kc = bi & 15, qt = (bi >> 4) & 15, b = bi >> 8;
  const int tid = threadIdx.x;
  const int lane = tid & 63, w = tid >> 6;
  const int l15 = lane & 15, g = lane >> 4;
  const int q0 = qt * 64 + w * 16, k0 = kc * 64;
  float am[4][4] = {};
#pragma unroll 1
  for (int h = 0; h < H_; h++) {
    {
      int r = tid >> 2, cs = (tid & 3) * 16;
      size_t krow = (size_t)(b * T_ + k0 + r) * 2048 + 1024 + h * DH_ + cs;
      *(uint4*)&Kh_s[r][cs]     = *(const uint4*)&QK[krow];
      *(uint4*)&Kh_s[r][cs + 8] = *(const uint4*)&QK[krow + 8];
    }
    __syncthreads();
    bf16x8 qh[2];
    {
      size_t qoff = (size_t)(b * T_ + q0 + l15) * 2048 + h * DH_;
      qh[0] = *(const bf16x8*)&QK[qoff + 8 * g];
      qh[1] = *(const bf16x8*)&QK[qoff + 32 + 8 * g];
    }
    f32x4 accs[4];
#pragma unroll
    for (int mf = 0; mf < 4; mf++) {
      accs[mf][0] = 0.f; accs[mf][1] = 0.f; accs[mf][2] = 0.f; accs[mf][3] = 0.f;
    }
#pragma unroll
    for (int mf = 0; mf < 4; mf++) {
#pragma unroll
      for (int ks = 0; ks < 2; ks++) {
        bf16x8 kh = *(bf16x8*)&Kh_s[mf * 16 + l15][ks * 32 + 8 * g];
        accs[mf] = __builtin_amdgcn_mfma_f32_16x16x32_bf16(kh, qh[ks], accs[mf], 0, 0, 0);
      }
    }
    const float mq = mrow[(b * H_ + h) * T_ + q0 + l15];
    const float li = linv[(b * H_ + h) * T_ + q0 + l15];
#pragma unroll
    for (int mf = 0; mf < 4; mf++)
#pragma unroll
      for (int r = 0; r < 4; r++)
        am[mf][r] += __builtin_amdgcn_exp2f(accs[mf][r] * SCALE2 - mq) * li;
    __syncthreads();
  }
  const float inv16 = 1.0f / 16.0f;
#pragma unroll
  for (int mf = 0; mf < 4; mf++) {
    float4 o;
    o.x = am[mf][0] * inv16; o.y = am[mf][1] * inv16;
    o.z = am[mf][2] * inv16; o.w = am[mf][3] * inv16;
    *(float4*)&am_out[(size_t)(b * T_ + q0 + l15) * T_ + k0 + 16 * mf + 4 * g] = o;
  }
}

// ---------------------------------------------------------------------------
extern "C" void kernel_launch(void* const* d_in, const int* in_sizes, int n_in,
                              void* d_out, int out_size, void* d_ws, size_t ws_size,
                              hipStream_t stream) {
  const float* x  = (const float*)d_in[0];
  const float* Wq = (const float*)d_in[1];
  const float* bq = (const float*)d_in[2];
  const float* Wk = (const float*)d_in[3];
  const float* bk = (const float*)d_in[4];
  const float* Wv = (const float*)d_in[5];
  const float* bv = (const float*)d_in[6];
  const float* Wo = (const float*)d_in[7];
  const float* bo = (const float*)d_in[8];

  float* out = (float*)d_out;                      // [B,T,D]
  float* am  = out + (size_t)B_ * T_ * D_;         // [B,T,T]

  char* w = (char*)d_ws;
  u16* QK    = (u16*)w; w += (size_t)4096 * 2048 * 2;  // Q cols 0..1023 | K 1024..2047
  u16* Vt    = (u16*)w; w += (size_t)64 * 4096 * 2;
  u16* xhi   = (u16*)w; w += (size_t)4096 * 1024 * 2;  // x-hi, then out_pre hi
  u16* WcThi = (u16*)w; w += (size_t)NCAT * 1024 * 2;
  u16* WoThi = (u16*)w; w += (size_t)1024 * 1024 * 2;
  float* mrow  = (float*)w; w += (size_t)B_ * H_ * T_ * 4;
  float* linvp = (float*)w; w += (size_t)B_ * H_ * T_ * 4;
  float* bcat  = (float*)w; w += (size_t)NCAT * 4;

  wprep<<<785, 256, 0, stream>>>(Wq, Wk, Wv, Wo, bq, bk, bv,
                                 WcThi, WoThi, bcat);
  rowconv<<<2048, 256, 0, stream>>>(x, xhi);

  // QKV GEMM (1-pass) -> QK bf16, Vt bf16
  mfma_gemm<128, true><<<dim3(32, 17), 256, 0, stream>>>(
      xhi, WcThi, bcat, nullptr, NCAT, 1024, 0, QK, Vt);

  attn_fused_mfma<<<1024, 256, 0, stream>>>(QK, Vt, mrow, linvp, xhi);
  attn_mean_mfma<<<1024, 256, 0, stream>>>(QK, mrow, linvp, am);

  // Wo GEMM (1-pass bf16)
  mfma_gemm<64, false><<<dim3(64, 8), 256, 0, stream>>>(
      xhi, WoThi, bo, out, 1024, 1024, 1024, nullptr, nullptr);
}